// Round 2
// baseline (558.672 us; speedup 1.0000x reference)
//
#include <hip/hip_runtime.h>

#define LAM 0.5f
#define MU 0.1f
#define RHO 0.05f
#define CLS 10
#define ROWS 256
#define SG 16   // s-values per block

__device__ __forceinline__ float waveReduceSum(float v) {
#pragma unroll
    for (int off = 32; off; off >>= 1) v += __shfl_down(v, off, 64);
    return v;
}

// Kernel 1: log-softmax of predictions -> logp[B*C], plus wstar accumulator
__global__ __launch_bounds__(256) void logp_kernel(
    const float* __restrict__ pred, const int* __restrict__ tgt,
    float* __restrict__ logp, float* __restrict__ wstar_acc, int B) {
    int b = blockIdx.x * 256 + threadIdx.x;
    float local = 0.f;
    if (b < B) {
        float x[CLS];
        const float2* p2 = reinterpret_cast<const float2*>(pred + (size_t)b * CLS);
#pragma unroll
        for (int j = 0; j < CLS / 2; j++) { float2 v = p2[j]; x[2 * j] = v.x; x[2 * j + 1] = v.y; }
        float m = x[0];
#pragma unroll
        for (int c = 1; c < CLS; c++) m = fmaxf(m, x[c]);
        float z = 0.f;
#pragma unroll
        for (int c = 0; c < CLS; c++) z += __expf(x[c] - m);
        float lse = m + __logf(z);
        float2* o2 = reinterpret_cast<float2*>(logp + (size_t)b * CLS);
#pragma unroll
        for (int j = 0; j < CLS / 2; j++)
            o2[j] = make_float2(x[2 * j] - lse, x[2 * j + 1] - lse);
        int t = tgt[b];
#pragma unroll
        for (int c = 0; c < CLS; c++) local += (c == t) ? (lse - x[c]) : 0.f;
    }
    float sum = waveReduceSum(local);
    if ((threadIdx.x & 63) == 0) atomicAdd(wstar_acc, sum);
}

// Kernel 2: streaming pass over noise, coalesced via padded LDS staging.
// Block = (s-group, row-chunk): owns ROWS rows, loops over SG s-values.
// logp row + target held in registers across the s-loop.
__global__ __launch_bounds__(256) void main_kernel(
    const float* __restrict__ noise, const float* __restrict__ logp,
    const int* __restrict__ tgt,
    float* __restrict__ accW, float* __restrict__ accWt, float* __restrict__ accN2,
    int B) {
    __shared__ float lds[ROWS * (CLS + 1)];  // stride-11 words: conflict-free row reads
    const int tid = threadIdx.x;
    const int nChunks = B / ROWS;            // 256
    const int chunk = blockIdx.x % nChunks;
    const int sg = blockIdx.x / nChunks;
    const int rowBase = chunk * ROWS;

    // Padded LDS word addresses for this thread's staged float4s (computed once).
    // flat word w -> padded index w + w/10  (row r word c -> 11r + c)
    const int w0 = tid * 4;
    const int w1 = (tid + 256) * 4;
    const int w2 = (tid + 512) * 4;
    const int a00 = w0 + w0 / 10, a01 = w0 + 1 + (w0 + 1) / 10,
              a02 = w0 + 2 + (w0 + 2) / 10, a03 = w0 + 3 + (w0 + 3) / 10;
    const int a10 = w1 + w1 / 10, a11 = w1 + 1 + (w1 + 1) / 10,
              a12 = w1 + 2 + (w1 + 2) / 10, a13 = w1 + 3 + (w1 + 3) / 10;
    const int a20 = w2 + w2 / 10, a21 = w2 + 1 + (w2 + 1) / 10,
              a22 = w2 + 2 + (w2 + 2) / 10, a23 = w2 + 3 + (w2 + 3) / 10;

    // ---- stage logp tile (coalesced float4) -> LDS -> registers ----
    {
        const float4* src = (const float4*)(logp + (size_t)rowBase * CLS);
        float4 v0 = src[tid];
        float4 v1 = src[tid + 256];
        lds[a00] = v0.x; lds[a01] = v0.y; lds[a02] = v0.z; lds[a03] = v0.w;
        lds[a10] = v1.x; lds[a11] = v1.y; lds[a12] = v1.z; lds[a13] = v1.w;
        if (tid < 128) {
            float4 v2 = src[tid + 512];
            lds[a20] = v2.x; lds[a21] = v2.y; lds[a22] = v2.z; lds[a23] = v2.w;
        }
    }
    __syncthreads();
    float lp[CLS];
    const int lbase = tid * (CLS + 1);
#pragma unroll
    for (int c = 0; c < CLS; c++) lp[c] = lds[lbase + c];
    const int t = tgt[rowBase + tid];
    const int lane = tid & 63;

#pragma unroll 1
    for (int si = 0; si < SG; si++) {
        const int s = sg * SG + si;
        // issue global loads before the barrier: latency overlaps other waves' compute
        const float4* src = (const float4*)(noise + ((size_t)s * B + rowBase) * CLS);
        float4 v0 = src[tid];
        float4 v1 = src[tid + 256];
        float4 v2 = make_float4(0.f, 0.f, 0.f, 0.f);
        if (tid < 128) v2 = src[tid + 512];
        __syncthreads();  // previous iteration's LDS reads complete
        lds[a00] = v0.x; lds[a01] = v0.y; lds[a02] = v0.z; lds[a03] = v0.w;
        lds[a10] = v1.x; lds[a11] = v1.y; lds[a12] = v1.z; lds[a13] = v1.w;
        if (tid < 128) {
            lds[a20] = v2.x; lds[a21] = v2.y; lds[a22] = v2.z; lds[a23] = v2.w;
        }
        __syncthreads();

        float Z = 0.f, Zl = 0.f, dot = 0.f, dotl = 0.f, sq = 0.f;
#pragma unroll
        for (int c = 0; c < CLS; c++) {
            float n = lds[lbase + c];
            float oh = (c == t) ? 1.f : 0.f;
            float e  = __expf(n + oh);
            float el = __expf(fmaf(LAM, n, oh));
            Z  += e;
            Zl += el;
            dot  = fmaf(e,  lp[c], dot);
            dotl = fmaf(el, lp[c], dotl);
            sq   = fmaf(n, n, sq);
        }
        float rw  = waveReduceSum(dot / Z);
        float rwt = waveReduceSum(dotl / Zl);
        float rn2 = waveReduceSum(sq);
        if (lane == 0) {
            atomicAdd(&accW[s],  rw);
            atomicAdd(&accWt[s], rwt);
            atomicAdd(&accN2[s], rn2);
        }
    }
}

// Kernel 3: epilogue — compute sc terms and final scalar.
__global__ __launch_bounds__(256) void final_kernel(
    const float* __restrict__ ws, float* __restrict__ out, int B, int S) {
    __shared__ float smem[4];
    int s = threadIdx.x;
    float invB = 1.0f / (float)B;
    float wstar = ws[3 * S] * invB;
    float local = 0.f;
    if (s < S) {
        float w  = -ws[s] * invB;
        float wt = -ws[S + s] * invB;
        float n2 = ws[2 * S + s];
        float sc1 = fmaxf(wstar - wt, 0.f);
        float sc2 = fmaxf(wstar - w + MU * n2 * 0.5f, 0.f);
        float sc3 = fmaxf(wt - (1.f - LAM) * wstar + LAM * w
                          + MU * LAM * (1.f - LAM) * n2 * 0.5f, 0.f);
        local = sc1 + sc2 + sc3;
    }
    float sum = waveReduceSum(local);
    int lane = threadIdx.x & 63, wid = threadIdx.x >> 6;
    if (lane == 0) smem[wid] = sum;
    __syncthreads();
    if (threadIdx.x == 0) {
        float sc = smem[0] + smem[1] + smem[2] + smem[3];
        out[0] = wstar + RHO * sc;
    }
}

extern "C" void kernel_launch(void* const* d_in, const int* in_sizes, int n_in,
                              void* d_out, int out_size, void* d_ws, size_t ws_size,
                              hipStream_t stream) {
    const float* pred  = (const float*)d_in[0];
    const int*   tgt   = (const int*)d_in[1];
    const float* noise = (const float*)d_in[2];
    float* out = (float*)d_out;

    int B = in_sizes[1];
    int S = in_sizes[2] / in_sizes[0];

    float* ws = (float*)d_ws;
    float* accW  = ws;
    float* accWt = ws + S;
    float* accN2 = ws + 2 * S;
    float* wstarAcc = ws + 3 * S;
    float* logp = ws + 512;   // 2048 B offset, 16 B aligned

    hipMemsetAsync(d_ws, 0, 2048, stream);

    logp_kernel<<<(B + 255) / 256, 256, 0, stream>>>(pred, tgt, logp, wstarAcc, B);

    int nChunks = B / ROWS;          // 256
    int nSG = S / SG;                // 8
    main_kernel<<<nSG * nChunks, 256, 0, stream>>>(noise, logp, tgt,
                                                   accW, accWt, accN2, B);

    final_kernel<<<1, 256, 0, stream>>>(ws, out, B, S);
}

// Round 3
// 83.027 us; speedup vs baseline: 6.7288x; 6.7288x over previous
//
#include <hip/hip_runtime.h>

#define LAM 0.5f
#define MU 0.1f
#define RHO 0.05f
#define CLS 10
#define ROWS 256
#define SG 16   // s-values per main-kernel block

__device__ __forceinline__ float waveReduceSum(float v) {
#pragma unroll
    for (int off = 32; off; off >>= 1) v += __shfl_down(v, off, 64);
    return v;
}

// Kernel 1: log-softmax of predictions -> logp[B*C] (coalesced via LDS staging),
// plus per-block-reduced wstar accumulator (1 atomic per block).
__global__ __launch_bounds__(256) void logp_kernel(
    const float* __restrict__ pred, const int* __restrict__ tgt,
    float* __restrict__ logp, float* __restrict__ wstar_acc, int B) {
    __shared__ float buf[ROWS * CLS];
    __shared__ float red[4];
    const int tid = threadIdx.x;
    const int rowBase = blockIdx.x * ROWS;

    // stage pred tile coalesced
    {
        const float4* src = (const float4*)(pred + (size_t)rowBase * CLS);
        float4* dst = (float4*)buf;
        dst[tid] = src[tid];
        dst[tid + 256] = src[tid + 256];
        if (tid < 128) dst[tid + 512] = src[tid + 512];
    }
    __syncthreads();
    float x[CLS];
    {
        const float2* b2 = (const float2*)buf;
#pragma unroll
        for (int j = 0; j < 5; j++) { float2 v = b2[tid * 5 + j]; x[2 * j] = v.x; x[2 * j + 1] = v.y; }
    }
    float m = x[0];
#pragma unroll
    for (int c = 1; c < CLS; c++) m = fmaxf(m, x[c]);
    float z = 0.f;
#pragma unroll
    for (int c = 0; c < CLS; c++) z += __expf(x[c] - m);
    float lse = m + __logf(z);
    int t = tgt[rowBase + tid];
    float local = 0.f;
#pragma unroll
    for (int c = 0; c < CLS; c++) local += (c == t) ? (lse - x[c]) : 0.f;

    // write logp rows back into buf, then copy out coalesced
    __syncthreads();
    {
        float2* b2 = (float2*)buf;
#pragma unroll
        for (int j = 0; j < 5; j++)
            b2[tid * 5 + j] = make_float2(x[2 * j] - lse, x[2 * j + 1] - lse);
    }
    __syncthreads();
    {
        float4* dst = (float4*)(logp + (size_t)rowBase * CLS);
        const float4* src = (const float4*)buf;
        dst[tid] = src[tid];
        dst[tid + 256] = src[tid + 256];
        if (tid < 128) dst[tid + 512] = src[tid + 512];
    }
    float sum = waveReduceSum(local);
    int lane = tid & 63, wid = tid >> 6;
    if (lane == 0) red[wid] = sum;
    __syncthreads();
    if (tid == 0) atomicAdd(wstar_acc, red[0] + red[1] + red[2] + red[3]);
}

// Kernel 2: streaming pass over noise. Block = (s-group, row-chunk).
// NO global atomics: per-iter wave partials -> LDS, block partials -> dedicated
// global slots partials[(s*3+k)*nChunks + chunk].
__global__ __launch_bounds__(256) void main_kernel(
    const float* __restrict__ noise, const float* __restrict__ logp,
    const int* __restrict__ tgt,
    float* __restrict__ partials, int B) {
    __shared__ float buf[ROWS * CLS];     // 10240 B, reused: logp stage then noise tiles
    __shared__ float part[4][SG][3];
    const int tid = threadIdx.x;
    const int nChunks = B / ROWS;         // 256
    const int chunk = blockIdx.x % nChunks;
    const int sg = blockIdx.x / nChunks;
    const int rowBase = chunk * ROWS;
    const int lane = tid & 63, wid = tid >> 6;

    // ---- stage logp tile coalesced -> registers ----
    {
        const float4* src = (const float4*)(logp + (size_t)rowBase * CLS);
        float4* dst = (float4*)buf;
        dst[tid] = src[tid];
        dst[tid + 256] = src[tid + 256];
        if (tid < 128) dst[tid + 512] = src[tid + 512];
    }
    __syncthreads();
    float lp[CLS];
    {
        const float2* b2 = (const float2*)buf;
#pragma unroll
        for (int j = 0; j < 5; j++) { float2 v = b2[tid * 5 + j]; lp[2 * j] = v.x; lp[2 * j + 1] = v.y; }
    }
    const int t = tgt[rowBase + tid];
    __syncthreads();   // buf free for reuse

#pragma unroll 1
    for (int si = 0; si < SG; si++) {
        const int s = sg * SG + si;
        const float4* src = (const float4*)(noise + ((size_t)s * B + (size_t)rowBase) * CLS);
        float4 v0 = src[tid];
        float4 v1 = src[tid + 256];
        float4 v2 = make_float4(0.f, 0.f, 0.f, 0.f);
        if (tid < 128) v2 = src[tid + 512];
        __syncthreads();   // previous iteration's LDS reads complete
        {
            float4* dst = (float4*)buf;
            dst[tid] = v0;
            dst[tid + 256] = v1;
            if (tid < 128) dst[tid + 512] = v2;
        }
        __syncthreads();

        float n[CLS];
        {
            const float2* b2 = (const float2*)buf;
#pragma unroll
            for (int j = 0; j < 5; j++) { float2 v = b2[tid * 5 + j]; n[2 * j] = v.x; n[2 * j + 1] = v.y; }
        }
        float Z = 0.f, Zl = 0.f, dot = 0.f, dotl = 0.f, sq = 0.f;
#pragma unroll
        for (int c = 0; c < CLS; c++) {
            float oh = (c == t) ? 1.f : 0.f;
            float e  = __expf(n[c] + oh);
            float el = __expf(fmaf(LAM, n[c], oh));
            Z  += e;
            Zl += el;
            dot  = fmaf(e,  lp[c], dot);
            dotl = fmaf(el, lp[c], dotl);
            sq   = fmaf(n[c], n[c], sq);
        }
        float rw  = waveReduceSum(dot / Z);
        float rwt = waveReduceSum(dotl / Zl);
        float rn2 = waveReduceSum(sq);
        if (lane == 0) {
            part[wid][si][0] = rw;
            part[wid][si][1] = rwt;
            part[wid][si][2] = rn2;
        }
    }
    __syncthreads();
    if (tid < SG * 3) {
        int si = tid / 3, k = tid % 3;
        float v = part[0][si][k] + part[1][si][k] + part[2][si][k] + part[3][si][k];
        int s = sg * SG + si;
        partials[(size_t)(s * 3 + k) * nChunks + chunk] = v;
    }
}

// Kernel 3: per-s reduction over chunks + hinge terms -> scAcc (128 atomics total).
__global__ __launch_bounds__(256) void reduce_kernel(
    const float* __restrict__ partials, const float* __restrict__ wsHead,
    float* __restrict__ scAcc, int B, int nChunks) {
    __shared__ float rA[4], rB[4], rC[4];
    const int s = blockIdx.x, tid = threadIdx.x;
    float a = partials[(size_t)(s * 3 + 0) * nChunks + tid];
    float b = partials[(size_t)(s * 3 + 1) * nChunks + tid];
    float c = partials[(size_t)(s * 3 + 2) * nChunks + tid];
    float ra = waveReduceSum(a), rb = waveReduceSum(b), rc = waveReduceSum(c);
    int lane = tid & 63, wid = tid >> 6;
    if (lane == 0) { rA[wid] = ra; rB[wid] = rb; rC[wid] = rc; }
    __syncthreads();
    if (tid == 0) {
        float invB = 1.0f / (float)B;
        float w  = -(rA[0] + rA[1] + rA[2] + rA[3]) * invB;
        float wt = -(rB[0] + rB[1] + rB[2] + rB[3]) * invB;
        float n2 =  (rC[0] + rC[1] + rC[2] + rC[3]);
        float wstar = wsHead[0] * invB;
        float sc1 = fmaxf(wstar - wt, 0.f);
        float sc2 = fmaxf(wstar - w + MU * n2 * 0.5f, 0.f);
        float sc3 = fmaxf(wt - (1.f - LAM) * wstar + LAM * w
                          + MU * LAM * (1.f - LAM) * n2 * 0.5f, 0.f);
        atomicAdd(scAcc, sc1 + sc2 + sc3);
    }
}

// Kernel 4: finalize scalar.
__global__ void finalize_kernel(const float* __restrict__ wsHead,
                                float* __restrict__ out, int B) {
    out[0] = wsHead[0] / (float)B + RHO * wsHead[1];
}

extern "C" void kernel_launch(void* const* d_in, const int* in_sizes, int n_in,
                              void* d_out, int out_size, void* d_ws, size_t ws_size,
                              hipStream_t stream) {
    const float* pred  = (const float*)d_in[0];
    const int*   tgt   = (const int*)d_in[1];
    const float* noise = (const float*)d_in[2];
    float* out = (float*)d_out;

    int B = in_sizes[1];
    int S = in_sizes[2] / in_sizes[0];
    int nChunks = B / ROWS;      // 256
    int nSG = S / SG;            // 8

    float* ws = (float*)d_ws;
    float* wsHead = ws;          // ws[0]=wstarAcc, ws[1]=scAcc
    float* logp = ws + 64;                         // 256 B offset
    float* partials = ws + 64 + (size_t)B * CLS;   // S*3*nChunks floats

    hipMemsetAsync(d_ws, 0, 256, stream);

    logp_kernel<<<B / ROWS, 256, 0, stream>>>(pred, tgt, logp, wsHead, B);

    main_kernel<<<nSG * nChunks, 256, 0, stream>>>(noise, logp, tgt, partials, B);

    reduce_kernel<<<S, 256, 0, stream>>>(partials, wsHead, wsHead + 1, B, nChunks);

    finalize_kernel<<<1, 1, 0, stream>>>(wsHead, out, B);
}

// Round 4
// 74.493 us; speedup vs baseline: 7.4997x; 1.1146x over previous
//
#include <hip/hip_runtime.h>

#define LAM 0.5f
#define MU 0.1f
#define RHO 0.05f
#define CLS 10
#define ROWS 256
#define SG 16
#define L2E  1.4426950408889634f
#define HL2E 0.7213475204444817f
#define EINV 0.36787944117144233f

typedef const __attribute__((address_space(1))) char gchar;
typedef __attribute__((address_space(3))) char lchar;

__device__ __forceinline__ float waveReduceSum(float v) {
#pragma unroll
    for (int m = 1; m < 64; m <<= 1) v += __shfl_xor(v, m, 64);
    return v;
}

// Stage 2560 B (64 rows x 10 floats) per wave: global -> LDS direct DMA.
// Each wave's slice is PRIVATE: written by its own DMA, read only by its own
// lanes (thread tid reads row tid; rows 64w..64w+63 live in wave w's slice).
// => no __syncthreads needed; per-wave counted vmcnt is the only sync.
__device__ __forceinline__ void dmaTile(const float4* srcBase, float* dstBase,
                                        int wid, int lane) {
    const float4* s = srcBase + wid * 160;
    float* d = dstBase + wid * 640;
    __builtin_amdgcn_global_load_lds((gchar*)(const char*)(s + lane),
                                     (lchar*)(char*)d, 16, 0, 0);
    __builtin_amdgcn_global_load_lds((gchar*)(const char*)(s + 64 + lane),
                                     (lchar*)(char*)(d + 256), 16, 0, 0);
    if (lane < 32)
        __builtin_amdgcn_global_load_lds((gchar*)(const char*)(s + 128 + lane),
                                         (lchar*)(char*)(d + 512), 16, 0, 0);
}

// Fused kernel: per-chunk logp (recomputed per s-group, trivial) + streaming
// noise pass with double-buffered DMA staging, zero barriers in the loop.
__global__ __launch_bounds__(256) void main_kernel(
    const float* __restrict__ noise, const float* __restrict__ pred,
    const int* __restrict__ tgt,
    float* __restrict__ wstarPart, float* __restrict__ partials, int B) {
    __shared__ float buf0[ROWS * CLS];   // 10240 B
    __shared__ float buf1[ROWS * CLS];   // 10240 B
    __shared__ float part[4][SG][3];
    __shared__ float red[4];
    const int tid = threadIdx.x;
    const int lane = tid & 63, wid = tid >> 6;
    const int nChunks = B / ROWS;            // 256
    const int chunk = blockIdx.x % nChunks;
    const int sg = blockIdx.x / nChunks;
    const int rowBase = chunk * ROWS;
    const int s0 = sg * SG;

    // the ONLY non-DMA global load before the loop: issue first
    const int t = tgt[rowBase + tid];

    const float4* predT = (const float4*)(pred + (size_t)rowBase * CLS);
    const size_t sStride4 = (size_t)B * CLS / 4;
    const float4* noiseT = (const float4*)(noise + (size_t)rowBase * CLS)
                           + (size_t)s0 * sStride4;

    dmaTile(predT, buf0, wid, lane);    // pred -> buf0   (3 outstanding)
    dmaTile(noiseT, buf1, wid, lane);   // s0   -> buf1   (6 outstanding)
    asm volatile("s_waitcnt vmcnt(3)" ::: "memory");   // pred (oldest 3+) done
    __builtin_amdgcn_sched_barrier(0);

    // ---- logp for this chunk (from wave-private buf0 slice) ----
    float x[CLS];
    {
        const float2* r2 = (const float2*)(buf0 + tid * CLS);
#pragma unroll
        for (int j = 0; j < 5; j++) { float2 v = r2[j]; x[2*j] = v.x; x[2*j+1] = v.y; }
    }
    float mx = x[0];
#pragma unroll
    for (int c = 1; c < CLS; c++) mx = fmaxf(mx, x[c]);
    float z = 0.f;
#pragma unroll
    for (int c = 0; c < CLS; c++) z += __expf(x[c] - mx);
    float lse = mx + __logf(z);

    float lp[CLS], lpk[CLS], kk[CLS], bias[CLS];
    float xt = 0.f;
#pragma unroll
    for (int c = 0; c < CLS; c++) {
        bool e = (c == t);
        float lpv = x[c] - lse;
        lp[c] = lpv;
        kk[c] = e ? EINV : 1.f;
        lpk[c] = lpv * kk[c];
        bias[c] = e ? L2E : 0.f;
        xt += e ? x[c] : 0.f;
    }
    {
        float rce = waveReduceSum(lse - xt);
        if (lane == 0) red[wid] = rce;
    }

    const float4* srcNext = noiseT + sStride4;

    // softmax(n+oh) via pl = exp2(fma(n,HL2E,bias)) = exp(n/2+oh):
    //   LAM-term uses pl directly; full term e = pl^2 * k (k = e^{-oh}).
#define BODY(CUR, NXT, SI)                                                     \
    {                                                                          \
        const int si = (SI);                                                   \
        if (si < SG - 1) {                                                     \
            dmaTile(srcNext, (NXT), wid, lane);                                \
            srcNext += sStride4;                                               \
            asm volatile("s_waitcnt vmcnt(3)" ::: "memory");                   \
        } else {                                                               \
            asm volatile("s_waitcnt vmcnt(0)" ::: "memory");                   \
        }                                                                      \
        __builtin_amdgcn_sched_barrier(0);                                     \
        float nn[CLS];                                                         \
        {                                                                      \
            const float2* r2 = (const float2*)((CUR) + tid * CLS);             \
            _Pragma("unroll")                                                  \
            for (int j = 0; j < 5; j++) {                                      \
                float2 v = r2[j]; nn[2*j] = v.x; nn[2*j+1] = v.y;              \
            }                                                                  \
        }                                                                      \
        float Z = 0.f, Zl = 0.f, dot = 0.f, dotl = 0.f, sq = 0.f;              \
        _Pragma("unroll")                                                      \
        for (int c = 0; c < CLS; c++) {                                        \
            float a  = fmaf(nn[c], HL2E, bias[c]);                             \
            float pl = exp2f(a);                                               \
            float t1 = pl * pl;                                                \
            Zl += pl;                                                          \
            dotl = fmaf(pl, lp[c], dotl);                                      \
            Z    = fmaf(t1, kk[c], Z);                                         \
            dot  = fmaf(t1, lpk[c], dot);                                      \
            sq   = fmaf(nn[c], nn[c], sq);                                     \
        }                                                                      \
        float rw  = waveReduceSum(__fdividef(dot, Z));                         \
        float rwt = waveReduceSum(__fdividef(dotl, Zl));                       \
        float rn2 = waveReduceSum(sq);                                         \
        if (lane == 0) {                                                       \
            part[wid][si][0] = rw;                                             \
            part[wid][si][1] = rwt;                                            \
            part[wid][si][2] = rn2;                                            \
        }                                                                      \
    }

    for (int sb = 0; sb < SG; sb += 2) {
        BODY(buf1, buf0, sb);
        BODY(buf0, buf1, sb + 1);
    }
#undef BODY

    __syncthreads();
    if (tid < SG * 3) {
        int si = tid / 3, ki = tid % 3;
        float v = part[0][si][ki] + part[1][si][ki] + part[2][si][ki] + part[3][si][ki];
        partials[((size_t)(s0 + si) * 3 + ki) * nChunks + chunk] = v;
    }
    if (sg == 0 && tid == 0)
        wstarPart[chunk] = red[0] + red[1] + red[2] + red[3];
}

// Per-s reduction over chunks -> sres[3*s+k]. No atomics.
__global__ __launch_bounds__(256) void reduce_kernel(
    const float* __restrict__ partials, float* __restrict__ sres, int nChunks) {
    __shared__ float rr[4][3];
    const int s = blockIdx.x, tid = threadIdx.x;
    const int lane = tid & 63, wid = tid >> 6;
    size_t base = (size_t)s * 3 * nChunks;
    float a = (tid < nChunks) ? partials[base + tid] : 0.f;
    float b = (tid < nChunks) ? partials[base + nChunks + tid] : 0.f;
    float c = (tid < nChunks) ? partials[base + 2 * (size_t)nChunks + tid] : 0.f;
    float ra = waveReduceSum(a), rb = waveReduceSum(b), rc = waveReduceSum(c);
    if (lane == 0) { rr[wid][0] = ra; rr[wid][1] = rb; rr[wid][2] = rc; }
    __syncthreads();
    if (tid < 3)
        sres[3 * s + tid] = rr[0][tid] + rr[1][tid] + rr[2][tid] + rr[3][tid];
}

// Finalize: wstar from wstarPart, hinge terms per s, scalar out.
__global__ __launch_bounds__(256) void finalize_kernel(
    const float* __restrict__ wstarPart, const float* __restrict__ sres,
    float* __restrict__ out, int B, int S, int nChunks) {
    __shared__ float red[4], red2[4];
    const int tid = threadIdx.x, lane = tid & 63, wid = tid >> 6;
    float invB = 1.0f / (float)B;
    float v = (tid < nChunks) ? wstarPart[tid] : 0.f;
    float rs = waveReduceSum(v);
    if (lane == 0) red[wid] = rs;
    __syncthreads();
    float wstar = (red[0] + red[1] + red[2] + red[3]) * invB;
    float local = 0.f;
    if (tid < S) {
        float w  = -sres[3 * tid + 0] * invB;
        float wt = -sres[3 * tid + 1] * invB;
        float n2 =  sres[3 * tid + 2];
        float sc1 = fmaxf(wstar - wt, 0.f);
        float sc2 = fmaxf(wstar - w + MU * n2 * 0.5f, 0.f);
        float sc3 = fmaxf(wt - (1.f - LAM) * wstar + LAM * w
                          + MU * LAM * (1.f - LAM) * n2 * 0.5f, 0.f);
        local = sc1 + sc2 + sc3;
    }
    float rsc = waveReduceSum(local);
    if (lane == 0) red2[wid] = rsc;
    __syncthreads();
    if (tid == 0) {
        float sc = red2[0] + red2[1] + red2[2] + red2[3];
        out[0] = wstar + RHO * sc;
    }
}

extern "C" void kernel_launch(void* const* d_in, const int* in_sizes, int n_in,
                              void* d_out, int out_size, void* d_ws, size_t ws_size,
                              hipStream_t stream) {
    const float* pred  = (const float*)d_in[0];
    const int*   tgt   = (const int*)d_in[1];
    const float* noise = (const float*)d_in[2];
    float* out = (float*)d_out;

    int B = in_sizes[1];                 // 65536
    int S = in_sizes[2] / in_sizes[0];   // 128
    int nChunks = B / ROWS;              // 256
    int nSG = S / SG;                    // 8

    float* ws = (float*)d_ws;
    float* wstarPart = ws;                          // [nChunks]
    float* partials  = ws + nChunks;                // [S*3*nChunks]
    float* sres      = partials + (size_t)S * 3 * nChunks;  // [3*S]

    // every slot written deterministically each call -> no memset needed
    main_kernel<<<nSG * nChunks, 256, 0, stream>>>(noise, pred, tgt,
                                                   wstarPart, partials, B);
    reduce_kernel<<<S, 256, 0, stream>>>(partials, sres, nChunks);
    finalize_kernel<<<1, 256, 0, stream>>>(wstarPart, sres, out, B, S, nChunks);
}